// Round 10
// baseline (2517.235 us; speedup 1.0000x reference)
//
#include <hip/hip_runtime.h>

typedef __bf16 bf16x8 __attribute__((ext_vector_type(8)));
typedef float  f32x4  __attribute__((ext_vector_type(4)));

union U4 { uint4 u; bf16x8 v; };
union U2Q { unsigned long long q[2]; bf16x8 v; };

__device__ __forceinline__ bf16x8 ld_frag(const void* p) {
    U4 t; t.u = *(const uint4*)p; return t.v;
}
__device__ __forceinline__ bf16x8 zfrag() {
    bf16x8 z;
#pragma unroll
    for (int jj = 0; jj < 8; jj++) z[jj] = (__bf16)0.f;
    return z;
}
// agent-scope (device, L3-coherent) accesses for cross-block h traffic
__device__ __forceinline__ bf16x8 ald_frag(const void* p) {
    U2Q t;
    unsigned long long* u = (unsigned long long*)p;
    t.q[0] = __hip_atomic_load(u,     __ATOMIC_RELAXED, __HIP_MEMORY_SCOPE_AGENT);
    t.q[1] = __hip_atomic_load(u + 1, __ATOMIC_RELAXED, __HIP_MEMORY_SCOPE_AGENT);
    return t.v;
}
__device__ __forceinline__ unsigned ald_u32(const void* p) {
    return __hip_atomic_load((const unsigned*)p, __ATOMIC_RELAXED, __HIP_MEMORY_SCOPE_AGENT);
}
__device__ __forceinline__ void ast_u32(void* p, unsigned v) {
    __hip_atomic_store((unsigned*)p, v, __ATOMIC_RELAXED, __HIP_MEMORY_SCOPE_AGENT);
}
__device__ __forceinline__ unsigned bf16_bits(float f) {
    __bf16 h = (__bf16)f; unsigned short s;
    __builtin_memcpy(&s, &h, 2); return (unsigned)s;
}
__device__ __forceinline__ float bf16_lo(unsigned v) {
    unsigned u = (v & 0xffffu) << 16; float f;
    __builtin_memcpy(&f, &u, 4); return f;
}
__device__ __forceinline__ float bf16_hi(unsigned v) {
    unsigned u = v & 0xffff0000u; float f;
    __builtin_memcpy(&f, &u, 4); return f;
}

__device__ __forceinline__ void gl_lds16(const uint4* g, void* l) {
    __builtin_amdgcn_global_load_lds(
        (const __attribute__((address_space(1))) unsigned int*)g,
        (__attribute__((address_space(3))) unsigned int*)l, 16, 0, 0);
}

__device__ __forceinline__ float sigf(float x) {
    return __builtin_amdgcn_rcpf(1.f + __expf(-x));
}
__device__ __forceinline__ float tanhf_fast(float x) {
    return 1.f - 2.f * __builtin_amdgcn_rcpf(1.f + __expf(2.f * x));
}

#define MFMA(A,B,C) C = __builtin_amdgcn_mfma_f32_16x16x32_bf16(A, B, C, 0, 0, 0)

// ---------------------------------------------------------------------------
// pack: [Wx(16,pad 32); Uh(256); Uh2(256)] -> B-fragments.
// For kt>=1 the 32 k-rows within a stage are permuted pi(p)=(p&1)*16+(p>>1);
// the h-slice storage uses the same permutation (paired-column dword I/O).
// kt=0 (x stage) keeps identity order (matches xpack).
// ---------------------------------------------------------------------------
__global__ void pack_kernel(const float* __restrict__ Wx, const float* __restrict__ Uh,
                            const float* __restrict__ Uh2, uint4* __restrict__ packW) {
    int tid = blockIdx.x * 256 + threadIdx.x;   // 4*17*48*64 = 208896
    int lane = tid & 63;
    int nt   = (tid >> 6) % 48;
    int kt   = ((tid >> 6) / 48) % 17;
    int a    = (tid >> 6) / (48 * 17);
    int col  = nt * 16 + (lane & 15);
    U4 u;
#pragma unroll
    for (int jj = 0; jj < 8; jj++) {
        int p  = (lane >> 4) * 8 + jj;
        int kk = (kt == 0) ? p : (((p & 1) << 4) | (p >> 1));
        int k  = kt * 32 + kk;
        float v;
        if (k < 16)       v = Wx[(a * 16 + k) * 768 + col];
        else if (k < 32)  v = 0.f;
        else if (k < 288) v = Uh[(a * 256 + (k - 32)) * 768 + col];
        else              v = Uh2[(a * 256 + (k - 288)) * 768 + col];
        u.v[jj] = (__bf16)v;
    }
    packW[tid] = u.u;
}

// xpack[a][i29][j29][m256][q2] = 8 bf16 of patch element k=q*8+jj
__global__ void xpack_kernel(const float* __restrict__ x, uint4* __restrict__ xp) {
    int tid = blockIdx.x * 256 + threadIdx.x;   // 1,722,368
    int q = tid & 1;
    int m = (tid >> 1) & 255;
    int rem = tid >> 9;
    int j = rem % 29;
    int t2 = rem / 29;
    int i = t2 % 29;
    int a = t2 / 29;
    int Ny = 29 - (a & 1), Nx = 29 - ((a >> 1) & 1);
    U4 u;
    if (i < Ny && j < Nx) {
        int y0 = (a & 1) ? (27 - i) : i;
        int x0 = (a & 2) ? (27 - j) : j;
        const float* px = x + m * 1024 + y0 * 32 + x0;
#pragma unroll
        for (int jj = 0; jj < 8; jj++) {
            int k = q * 8 + jj;
            u.v[jj] = (__bf16)px[(k >> 2) * 32 + (k & 3)];
        }
    } else {
#pragma unroll
        for (int jj = 0; jj < 8; jj++) u.v[jj] = (__bf16)0.f;
    }
    xp[tid] = u.u;
}

// ---------------------------------------------------------------------------
// Dataflow persistent kernel (R9 structure; R10 = single-lane polling).
//   G = bx&31 : group (a = G>>3 direction, s8 = G&7 batch-slice of M32)
//   g  = bx>>5: 32-hidden-col split (B for (a,g) in 102 KB LDS, loaded once)
// Note bx≡G (mod 8): a group's 8 g-blocks co-locate on one XCD (perf only).
// Wave w owns a contiguous column strip, row-major scan (deadlock-free, R9).
// Sync: monotone counters in L3 (agent atomics), no barriers/fences:
//   prog[G][j] = #(cell,g) completions of column j; cons[G][j] = of column j+1.
// R9 pathology: 64-lane same-address ATOMIC polls don't broadcast-coalesce ->
// 64 serialized L3 ops per poll x 64 waves hammering 2 cachelines; producers'
// atomicAdd queued behind the storm (~50k cyc/hop). Fix: poll in lane 0 only,
// broadcast via readfirstlane (64x less counter traffic).
// hbuf per group: [j29][slot3][kt8][m32][c32perm] bf16 (slice 16 KB).
// ---------------------------------------------------------------------------
__global__ __launch_bounds__(512, 2) void persist_kernel(
    const float* __restrict__ x, const uint4* __restrict__ xpack,
    const uint4* __restrict__ packW, const float* __restrict__ bias,
    char* __restrict__ hbuf, unsigned* __restrict__ flags)
{
    extern __shared__ __align__(16) unsigned char smem[];   // 104448 B

    int bx = blockIdx.x;
    int G  = bx & 31;
    int g  = bx >> 5;
    int a  = G >> 3, s8 = G & 7;
    int Ny = 29 - (a & 1), Nx = 29 - ((a >> 1) & 1);
    char* hbg = hbuf + (size_t)G * 1425408;
    unsigned* prog = flags + G * 32;
    unsigned* cons = flags + 1024 + G * 32;

    int tid  = threadIdx.x;
    int w8   = tid >> 6;          // wave = strip owner
    int lane = tid & 63;
    int q    = lane >> 4;
    int l16  = lane & 15;

    // ---- one-time B preload: 102 chunks x 1 KB ----
    for (int c = w8; c < 102; c += 8) {
        int s  = c / 6;
        int cc = c - s * 6;
        int kt = (s == 16) ? 0 : (s + 1);
        int nt = (cc >> 1) * 16 + 2 * g + (cc & 1);
        gl_lds16(packW + (size_t)(a * 17 + kt) * 3072 + nt * 64 + lane,
                 smem + (size_t)c * 1024);
    }
    __syncthreads();   // the only barrier in the kernel

    const float* ba = bias + a * 768;
    int c0 = g * 32 + l16;
    float bR0 = ba[c0],      bZ0 = ba[256 + c0],      bN0 = ba[512 + c0];
    float bR1 = ba[c0 + 16], bZ1 = ba[256 + c0 + 16], bN1 = ba[512 + c0 + 16];

    // single-lane poll + wave broadcast (R10 fix)
    auto wait_ge = [&](unsigned* f, unsigned v) {
        for (;;) {
            unsigned cur = 0;
            if (lane == 0) cur = ald_u32(f);
            cur = __builtin_amdgcn_readfirstlane(cur);
            if ((int)cur >= (int)v) break;
            __builtin_amdgcn_s_sleep(2);
        }
        __asm__ volatile("" ::: "memory");
    };

    // contiguous strip for wave w8
    int sbase = Nx >> 3, srem = Nx & 7;
    int js = w8 * sbase + (w8 < srem ? w8 : srem);
    int je = js + sbase + (w8 < srem ? 1 : 0);   // exclusive

    for (int i = 0; i < Ny; ++i) {
        for (int j = js; j < je; ++j) {
            bool hasA = (i > 0);
            bool hasL = (j > 0);

            // x-stage A fragments (plain cached; issue before spins)
            bf16x8 afx[2];
            if (xpack) {
                const uint4* xpc = xpack + (size_t)((a * 29 + i) * 29 + j) * 512
                                  + (size_t)(s8 * 32) * 2 + q;
#pragma unroll
                for (int mt = 0; mt < 2; mt++) {
                    if (q < 2) afx[mt] = ld_frag(xpc + (mt * 16 + l16) * 2);
                    else       afx[mt] = zfrag();
                }
            } else {
                int y0 = (a & 1) ? (27 - i) : i;
                int x0 = (a & 2) ? (27 - j) : j;
#pragma unroll
                for (int mt = 0; mt < 2; mt++) {
                    if (q < 2) {
                        int m = s8 * 32 + mt * 16 + l16;
                        const float* xp = x + m * 1024 + (y0 + 2 * q) * 32 + x0;
#pragma unroll
                        for (int jj = 0; jj < 8; jj++)
                            afx[mt][jj] = (__bf16)xp[(jj >> 2) * 32 + (jj & 3)];
                    } else afx[mt] = zfrag();
                }
            }

            // ---- dataflow waits ----
            if (hasA) wait_ge(prog + j, 8u * (unsigned)i);
            if (hasL) wait_ge(prog + j - 1, 8u * (unsigned)(i + 1));

            const char* sA = hbg + (size_t)(j * 3 + ((i - 1) % 3)) * 16384;
            const char* sL = hbg + (size_t)((j - 1) * 3 + (i % 3)) * 16384;

            // ---- issue all A-fragment loads (agent/L3) ----
            bf16x8 afA[8][2], afL[8][2];
            unsigned hsA[8], hsL[8];
            if (hasA) {
#pragma unroll
                for (int kt = 0; kt < 8; kt++)
#pragma unroll
                    for (int mt = 0; mt < 2; mt++)
                        afA[kt][mt] = ald_frag(sA + kt * 2048 + (mt * 16 + l16) * 64 + q * 16);
#pragma unroll
                for (int mt = 0; mt < 2; mt++)
#pragma unroll
                    for (int e = 0; e < 4; e++)
                        hsA[mt * 4 + e] = ald_u32(sA + g * 2048 + (mt * 16 + q * 4 + e) * 64 + l16 * 4);
            }
            if (hasL) {
#pragma unroll
                for (int kt = 0; kt < 8; kt++)
#pragma unroll
                    for (int mt = 0; mt < 2; mt++)
                        afL[kt][mt] = ald_frag(sL + kt * 2048 + (mt * 16 + l16) * 64 + q * 16);
#pragma unroll
                for (int mt = 0; mt < 2; mt++)
#pragma unroll
                    for (int e = 0; e < 4; e++)
                        hsL[mt * 4 + e] = ald_u32(sL + g * 2048 + (mt * 16 + q * 4 + e) * 64 + l16 * 4);
            }

            f32x4 acc[2][6];
#pragma unroll
            for (int mt = 0; mt < 2; mt++)
#pragma unroll
                for (int cf = 0; cf < 6; cf++)
#pragma unroll
                    for (int e = 0; e < 4; e++) acc[mt][cf][e] = 0.f;

            // ---- x-stage: r,z into acc[.][0..3]; n-part into tn ----
            f32x4 tn0[2], tn1[2];
            {
                const unsigned char* bb = smem + (size_t)16 * 6144 + lane * 16;
#pragma unroll
                for (int cf = 0; cf < 4; cf++) {
                    bf16x8 bf = ld_frag(bb + cf * 1024);
#pragma unroll
                    for (int mt = 0; mt < 2; mt++) MFMA(afx[mt], bf, acc[mt][cf]);
                }
                bf16x8 bn0 = ld_frag(bb + 4 * 1024);
                bf16x8 bn1 = ld_frag(bb + 5 * 1024);
#pragma unroll
                for (int mt = 0; mt < 2; mt++) {
                    f32x4 z4 = {0.f, 0.f, 0.f, 0.f};
                    tn0[mt] = __builtin_amdgcn_mfma_f32_16x16x32_bf16(afx[mt], bn0, z4, 0, 0, 0);
                    tn1[mt] = __builtin_amdgcn_mfma_f32_16x16x32_bf16(afx[mt], bn1, z4, 0, 0, 0);
                }
            }

            // ---- 16 h-stages ----
            if (hasA) {
#pragma unroll
                for (int s = 0; s < 8; s++) {
                    const unsigned char* bb = smem + (size_t)s * 6144 + lane * 16;
#pragma unroll
                    for (int cf = 0; cf < 6; cf++) {
                        bf16x8 bf = ld_frag(bb + cf * 1024);
#pragma unroll
                        for (int mt = 0; mt < 2; mt++) MFMA(afA[s][mt], bf, acc[mt][cf]);
                    }
                }
            }
            if (hasL) {
#pragma unroll
                for (int s = 0; s < 8; s++) {
                    const unsigned char* bb = smem + (size_t)(8 + s) * 6144 + lane * 16;
#pragma unroll
                    for (int cf = 0; cf < 6; cf++) {
                        bf16x8 bf = ld_frag(bb + cf * 1024);
#pragma unroll
                        for (int mt = 0; mt < 2; mt++) MFMA(afL[s][mt], bf, acc[mt][cf]);
                    }
                }
            }

            // ---- back-pressure before overwriting slot (j, i%3) ----
            if (j < Nx - 1 && i >= 3) wait_ge(cons + j, 8u * (unsigned)(i - 2));

            // ---- epilogue: gates, state update, agent dword stores ----
            char* sO = hbg + (size_t)(j * 3 + (i % 3)) * 16384;
#pragma unroll
            for (int mt = 0; mt < 2; mt++) {
#pragma unroll
                for (int e = 0; e < 4; e++) {
                    int m = mt * 16 + q * 4 + e;
                    float rv0 = sigf(acc[mt][0][e] + bR0);
                    float zv0 = sigf(acc[mt][2][e] + bZ0);
                    float nv0 = tanhf_fast(tn0[mt][e] + bN0 + rv0 * acc[mt][4][e]);
                    float rv1 = sigf(acc[mt][1][e] + bR1);
                    float zv1 = sigf(acc[mt][3][e] + bZ1);
                    float nv1 = tanhf_fast(tn1[mt][e] + bN1 + rv1 * acc[mt][5][e]);
                    float hs0 = 0.f, hs1 = 0.f;
                    if (hasA) {
                        unsigned v = hsA[mt * 4 + e];
                        hs0 += bf16_lo(v); hs1 += bf16_hi(v);
                    }
                    if (hasL) {
                        unsigned v = hsL[mt * 4 + e];
                        hs0 += bf16_lo(v); hs1 += bf16_hi(v);
                    }
                    float h0 = (1.f - zv0) * nv0 + 0.5f * zv0 * hs0;
                    float h1 = (1.f - zv1) * nv1 + 0.5f * zv1 * hs1;
                    ast_u32(sO + (size_t)g * 2048 + (size_t)m * 64 + l16 * 4,
                            bf16_bits(h0) | (bf16_bits(h1) << 16));
                }
            }

            __builtin_amdgcn_s_waitcnt(0);   // h stores at coherence point
            if (lane == 0) {
                __hip_atomic_fetch_add(prog + j, 1u, __ATOMIC_RELAXED,
                                       __HIP_MEMORY_SCOPE_AGENT);
                if (hasL)
                    __hip_atomic_fetch_add(cons + j - 1, 1u, __ATOMIC_RELAXED,
                                           __HIP_MEMORY_SCOPE_AGENT);
            }
        }
    }
}

// ---------------------------------------------------------------------------
// Output: logits = hcat @ W_out + b_out, then log_softmax. One wave per batch.
// ---------------------------------------------------------------------------
__global__ __launch_bounds__(64) void out_kernel(const char* __restrict__ hbuf,
    const float* __restrict__ Wout, const float* __restrict__ bout,
    float* __restrict__ out)
{
    int b = blockIdx.x;
    int tt = threadIdx.x;
    float accv[10];
#pragma unroll
    for (int o = 0; o < 10; o++) accv[o] = 0.f;
    for (int it = 0; it < 16; ++it) {
        int k = it * 64 + tt;
        int a = k >> 8, c = k & 255;
        int Ny = 29 - (a & 1), Nx = 29 - ((a >> 1) & 1);
        int G  = a * 8 + (b >> 5);
        int c31 = c & 31;
        int pos = ((c31 & 15) << 1) | (c31 >> 4);
        const __bf16* hp = (const __bf16*)(hbuf + (size_t)G * 1425408
                           + (size_t)((Nx - 1) * 3 + (Ny - 1) % 3) * 16384
                           + (size_t)(c >> 5) * 2048 + (size_t)(b & 31) * 64
                           + (size_t)pos * 2);
        float h = (float)(*hp);
        const float* wr = Wout + k * 10;
#pragma unroll
        for (int o = 0; o < 10; o++) accv[o] += h * wr[o];
    }
#pragma unroll
    for (int off = 32; off > 0; off >>= 1)
#pragma unroll
        for (int o = 0; o < 10; o++) accv[o] += __shfl_down(accv[o], off, 64);
    if (tt == 0) {
        float l[10];
#pragma unroll
        for (int o = 0; o < 10; o++) l[o] = accv[o] + bout[o];
        float mx = l[0];
#pragma unroll
        for (int o = 1; o < 10; o++) mx = fmaxf(mx, l[o]);
        float se = 0.f;
#pragma unroll
        for (int o = 0; o < 10; o++) se += __expf(l[o] - mx);
        float lse = mx + __logf(se);
#pragma unroll
        for (int o = 0; o < 10; o++) out[b * 10 + o] = l[o] - lse;
    }
}

extern "C" void kernel_launch(void* const* d_in, const int* in_sizes, int n_in,
                              void* d_out, int out_size, void* d_ws, size_t ws_size,
                              hipStream_t stream) {
    const float* x    = (const float*)d_in[0];
    const float* Wx   = (const float*)d_in[1];
    const float* Uh   = (const float*)d_in[2];
    const float* Uh2  = (const float*)d_in[3];
    const float* b    = (const float*)d_in[4];
    const float* Wout = (const float*)d_in[5];
    const float* bout = (const float*)d_in[6];
    float* out = (float*)d_out;

    char* ws = (char*)d_ws;
    const size_t PACK_PAD   = 3407872;
    const size_t XPACK_END  = 31457280;     // pack + xpack (padded)
    const size_t HBUF_BYTES = 45613056;     // 32 * 29 * 3 * 16384
    const size_t FLAG_BYTES = 8192;
    bool use_xp = (ws_size >= XPACK_END + HBUF_BYTES + FLAG_BYTES);

    uint4*  packW = (uint4*)ws;
    uint4*  xpack = use_xp ? (uint4*)(ws + PACK_PAD) : nullptr;
    size_t  hbuf_off = use_xp ? XPACK_END : PACK_PAD;
    char*   hbuf  = ws + hbuf_off;
    unsigned* flags = (unsigned*)(ws + hbuf_off + HBUF_BYTES);

    (void)hipFuncSetAttribute((const void*)persist_kernel,
                              hipFuncAttributeMaxDynamicSharedMemorySize, 104448);

    hipMemsetAsync(flags, 0, FLAG_BYTES, stream);
    pack_kernel<<<816, 256, 0, stream>>>(Wx, Uh, Uh2, packW);
    if (use_xp)
        xpack_kernel<<<6728, 256, 0, stream>>>(x, xpack);

    void* args[] = { (void*)&x, (void*)&xpack, (void*)&packW, (void*)&b,
                     (void*)&hbuf, (void*)&flags };
    hipLaunchCooperativeKernel((void*)persist_kernel, dim3(256), dim3(512),
                               args, 104448, stream);

    out_kernel<<<256, 64, 0, stream>>>(hbuf, Wout, bout, out);
}

// Round 12
// 1892.795 us; speedup vs baseline: 1.3299x; 1.3299x over previous
//
#include <hip/hip_runtime.h>

typedef __bf16 bf16x8 __attribute__((ext_vector_type(8)));
typedef float  f32x4  __attribute__((ext_vector_type(4)));

union U4 { uint4 u; bf16x8 v; };

__device__ __forceinline__ bf16x8 ld_frag(const void* p) {
    U4 t; t.u = *(const uint4*)p; return t.v;
}
__device__ __forceinline__ bf16x8 zfrag() {
    bf16x8 z;
#pragma unroll
    for (int jj = 0; jj < 8; jj++) z[jj] = (__bf16)0.f;
    return z;
}
// ---- L2-bypassing (sc0 sc1) PLAIN loads/stores: same cross-XCD visibility as
// agent-scope atomics (L3 = coherence point) but coalescing + pipelined.
// R9/R10 lesson: per-lane ATOMIC loads/stores don't coalesce -> ~3.6k serialized
// fabric ops per cell; these emit ~100 coalesced 64B requests instead.
__device__ __forceinline__ void ld16_sc01(const void* p, uint4* d) {
    asm volatile("global_load_dwordx4 %0, %1, off sc0 sc1" : "=v"(*d) : "v"(p));
}
__device__ __forceinline__ void ld4_sc01(const void* p, unsigned* d) {
    asm volatile("global_load_dword %0, %1, off sc0 sc1" : "=v"(*d) : "v"(p));
}
__device__ __forceinline__ void st4_sc01(void* p, unsigned v) {
    asm volatile("global_store_dword %0, %1, off sc0 sc1" :: "v"(p), "v"(v) : "memory");
}
__device__ __forceinline__ void wait_vm0() {
    asm volatile("s_waitcnt vmcnt(0)" ::: "memory");
}
// scalar-component register pin (R11 compile fix: tied multi-reg operands are
// unsupported; tied 32-bit scalars are fine). Zero instructions emitted.
#define PIN32(x) asm volatile("" : "+v"(x))
__device__ __forceinline__ void pin_u4(uint4& u) {
    PIN32(u.x); PIN32(u.y); PIN32(u.z); PIN32(u.w);
}

__device__ __forceinline__ unsigned ald_u32(const void* p) {
    return __hip_atomic_load((const unsigned*)p, __ATOMIC_RELAXED, __HIP_MEMORY_SCOPE_AGENT);
}
__device__ __forceinline__ unsigned bf16_bits(float f) {
    __bf16 h = (__bf16)f; unsigned short s;
    __builtin_memcpy(&s, &h, 2); return (unsigned)s;
}
__device__ __forceinline__ float bf16_lo(unsigned v) {
    unsigned u = (v & 0xffffu) << 16; float f;
    __builtin_memcpy(&f, &u, 4); return f;
}
__device__ __forceinline__ float bf16_hi(unsigned v) {
    unsigned u = v & 0xffff0000u; float f;
    __builtin_memcpy(&f, &u, 4); return f;
}

__device__ __forceinline__ void gl_lds16(const uint4* g, void* l) {
    __builtin_amdgcn_global_load_lds(
        (const __attribute__((address_space(1))) unsigned int*)g,
        (__attribute__((address_space(3))) unsigned int*)l, 16, 0, 0);
}

__device__ __forceinline__ float sigf(float x) {
    return __builtin_amdgcn_rcpf(1.f + __expf(-x));
}
__device__ __forceinline__ float tanhf_fast(float x) {
    return 1.f - 2.f * __builtin_amdgcn_rcpf(1.f + __expf(2.f * x));
}

#define MFMA(A,B,C) C = __builtin_amdgcn_mfma_f32_16x16x32_bf16(A, B, C, 0, 0, 0)

// ---------------------------------------------------------------------------
// pack: [Wx(16,pad 32); Uh(256); Uh2(256)] -> B-fragments.
// For kt>=1 the 32 k-rows within a stage are permuted pi(p)=(p&1)*16+(p>>1);
// the h-slice storage uses the same permutation (paired-column dword I/O).
// kt=0 (x stage) keeps identity order (matches xpack).
// ---------------------------------------------------------------------------
__global__ void pack_kernel(const float* __restrict__ Wx, const float* __restrict__ Uh,
                            const float* __restrict__ Uh2, uint4* __restrict__ packW) {
    int tid = blockIdx.x * 256 + threadIdx.x;   // 4*17*48*64 = 208896
    int lane = tid & 63;
    int nt   = (tid >> 6) % 48;
    int kt   = ((tid >> 6) / 48) % 17;
    int a    = (tid >> 6) / (48 * 17);
    int col  = nt * 16 + (lane & 15);
    U4 u;
#pragma unroll
    for (int jj = 0; jj < 8; jj++) {
        int p  = (lane >> 4) * 8 + jj;
        int kk = (kt == 0) ? p : (((p & 1) << 4) | (p >> 1));
        int k  = kt * 32 + kk;
        float v;
        if (k < 16)       v = Wx[(a * 16 + k) * 768 + col];
        else if (k < 32)  v = 0.f;
        else if (k < 288) v = Uh[(a * 256 + (k - 32)) * 768 + col];
        else              v = Uh2[(a * 256 + (k - 288)) * 768 + col];
        u.v[jj] = (__bf16)v;
    }
    packW[tid] = u.u;
}

// xpack[a][i29][j29][m256][q2] = 8 bf16 of patch element k=q*8+jj
__global__ void xpack_kernel(const float* __restrict__ x, uint4* __restrict__ xp) {
    int tid = blockIdx.x * 256 + threadIdx.x;   // 1,722,368
    int q = tid & 1;
    int m = (tid >> 1) & 255;
    int rem = tid >> 9;
    int j = rem % 29;
    int t2 = rem / 29;
    int i = t2 % 29;
    int a = t2 / 29;
    int Ny = 29 - (a & 1), Nx = 29 - ((a >> 1) & 1);
    U4 u;
    if (i < Ny && j < Nx) {
        int y0 = (a & 1) ? (27 - i) : i;
        int x0 = (a & 2) ? (27 - j) : j;
        const float* px = x + m * 1024 + y0 * 32 + x0;
#pragma unroll
        for (int jj = 0; jj < 8; jj++) {
            int k = q * 8 + jj;
            u.v[jj] = (__bf16)px[(k >> 2) * 32 + (k & 3)];
        }
    } else {
#pragma unroll
        for (int jj = 0; jj < 8; jj++) u.v[jj] = (__bf16)0.f;
    }
    xp[tid] = u.u;
}

// ---------------------------------------------------------------------------
// Dataflow persistent kernel (R9/R10 structure; R12 = coalesced sc0sc1 h I/O).
//   G = bx&31 : group (a = G>>3 direction, s8 = G&7 batch-slice of M32)
//   g  = bx>>5: 32-hidden-col split (B for (a,g) in 102 KB LDS, loaded once)
// Wave w owns a contiguous column strip, row-major scan (deadlock-free, R9).
// Sync: monotone counters (agent atomics, 1 op/wave/cell), single-lane polled.
//   prog[G][j] = #(cell,g) completions of column j; cons[G][j] = of column j+1.
// h data: plain global loads/stores with sc0 sc1 (L1/L2 bypass -> L3 coherence
// point; placement-independent) + manual vmcnt(0) + scalar-pin for ordering.
// hbuf per group: [j29][slot3][kt8][m32][c32perm] bf16 (slice 16 KB).
// ---------------------------------------------------------------------------
__global__ __launch_bounds__(512, 2) void persist_kernel(
    const float* __restrict__ x, const uint4* __restrict__ xpack,
    const uint4* __restrict__ packW, const float* __restrict__ bias,
    char* __restrict__ hbuf, unsigned* __restrict__ flags)
{
    extern __shared__ __align__(16) unsigned char smem[];   // 104448 B

    int bx = blockIdx.x;
    int G  = bx & 31;
    int g  = bx >> 5;
    int a  = G >> 3, s8 = G & 7;
    int Ny = 29 - (a & 1), Nx = 29 - ((a >> 1) & 1);
    char* hbg = hbuf + (size_t)G * 1425408;
    unsigned* prog = flags + G * 32;
    unsigned* cons = flags + 1024 + G * 32;

    int tid  = threadIdx.x;
    int w8   = tid >> 6;          // wave = strip owner
    int lane = tid & 63;
    int q    = lane >> 4;
    int l16  = lane & 15;

    // ---- one-time B preload: 102 chunks x 1 KB ----
    for (int c = w8; c < 102; c += 8) {
        int s  = c / 6;
        int cc = c - s * 6;
        int kt = (s == 16) ? 0 : (s + 1);
        int nt = (cc >> 1) * 16 + 2 * g + (cc & 1);
        gl_lds16(packW + (size_t)(a * 17 + kt) * 3072 + nt * 64 + lane,
                 smem + (size_t)c * 1024);
    }
    __syncthreads();   // the only barrier in the kernel

    const float* ba = bias + a * 768;
    int c0 = g * 32 + l16;
    float bR0 = ba[c0],      bZ0 = ba[256 + c0],      bN0 = ba[512 + c0];
    float bR1 = ba[c0 + 16], bZ1 = ba[256 + c0 + 16], bN1 = ba[512 + c0 + 16];

    // single-lane poll + wave broadcast
    auto wait_ge = [&](unsigned* f, unsigned v) {
        for (;;) {
            unsigned cur = 0;
            if (lane == 0) cur = ald_u32(f);
            cur = __builtin_amdgcn_readfirstlane(cur);
            if ((int)cur >= (int)v) break;
            __builtin_amdgcn_s_sleep(2);
        }
        __asm__ volatile("" ::: "memory");
    };

    // contiguous strip for wave w8
    int sbase = Nx >> 3, srem = Nx & 7;
    int js = w8 * sbase + (w8 < srem ? w8 : srem);
    int je = js + sbase + (w8 < srem ? 1 : 0);   // exclusive

    for (int i = 0; i < Ny; ++i) {
        for (int j = js; j < je; ++j) {
            bool hasA = (i > 0);
            bool hasL = (j > 0);

            // x-stage A fragments (plain cached)
            bf16x8 afx[2];
            if (xpack) {
                const uint4* xpc = xpack + (size_t)((a * 29 + i) * 29 + j) * 512
                                  + (size_t)(s8 * 32) * 2 + q;
#pragma unroll
                for (int mt = 0; mt < 2; mt++) {
                    if (q < 2) afx[mt] = ld_frag(xpc + (mt * 16 + l16) * 2);
                    else       afx[mt] = zfrag();
                }
            } else {
                int y0 = (a & 1) ? (27 - i) : i;
                int x0 = (a & 2) ? (27 - j) : j;
#pragma unroll
                for (int mt = 0; mt < 2; mt++) {
                    if (q < 2) {
                        int m = s8 * 32 + mt * 16 + l16;
                        const float* xp = x + m * 1024 + (y0 + 2 * q) * 32 + x0;
#pragma unroll
                        for (int jj = 0; jj < 8; jj++)
                            afx[mt][jj] = (__bf16)xp[(jj >> 2) * 32 + (jj & 3)];
                    } else afx[mt] = zfrag();
                }
            }

            // ---- dataflow waits ----
            if (hasA) wait_ge(prog + j, 8u * (unsigned)i);
            if (hasL) wait_ge(prog + j - 1, 8u * (unsigned)(i + 1));

            const char* sA = hbg + (size_t)(j * 3 + ((i - 1) % 3)) * 16384;
            const char* sL = hbg + (size_t)((j - 1) * 3 + (i % 3)) * 16384;

            // ---- issue coalesced sc0sc1 loads for all A fragments ----
            U4 rA[8][2], rL[8][2];
            unsigned hsA[8], hsL[8];
            if (hasA) {
#pragma unroll
                for (int kt = 0; kt < 8; kt++)
#pragma unroll
                    for (int mt = 0; mt < 2; mt++)
                        ld16_sc01(sA + kt * 2048 + (mt * 16 + l16) * 64 + q * 16,
                                  &rA[kt][mt].u);
#pragma unroll
                for (int mt = 0; mt < 2; mt++)
#pragma unroll
                    for (int e = 0; e < 4; e++)
                        ld4_sc01(sA + g * 2048 + (mt * 16 + q * 4 + e) * 64 + l16 * 4,
                                 &hsA[mt * 4 + e]);
            }
            if (hasL) {
#pragma unroll
                for (int kt = 0; kt < 8; kt++)
#pragma unroll
                    for (int mt = 0; mt < 2; mt++)
                        ld16_sc01(sL + kt * 2048 + (mt * 16 + l16) * 64 + q * 16,
                                  &rL[kt][mt].u);
#pragma unroll
                for (int mt = 0; mt < 2; mt++)
#pragma unroll
                    for (int e = 0; e < 4; e++)
                        ld4_sc01(sL + g * 2048 + (mt * 16 + q * 4 + e) * 64 + l16 * 4,
                                 &hsL[mt * 4 + e]);
            }
            wait_vm0();
            // pin post-wait values (uses below can't be hoisted above the wait)
            if (hasA) {
#pragma unroll
                for (int kt = 0; kt < 8; kt++)
#pragma unroll
                    for (int mt = 0; mt < 2; mt++) pin_u4(rA[kt][mt].u);
#pragma unroll
                for (int e = 0; e < 8; e++) PIN32(hsA[e]);
            }
            if (hasL) {
#pragma unroll
                for (int kt = 0; kt < 8; kt++)
#pragma unroll
                    for (int mt = 0; mt < 2; mt++) pin_u4(rL[kt][mt].u);
#pragma unroll
                for (int e = 0; e < 8; e++) PIN32(hsL[e]);
            }

            f32x4 acc[2][6];
#pragma unroll
            for (int mt = 0; mt < 2; mt++)
#pragma unroll
                for (int cf = 0; cf < 6; cf++)
#pragma unroll
                    for (int e = 0; e < 4; e++) acc[mt][cf][e] = 0.f;

            // ---- x-stage: r,z into acc[.][0..3]; n-part into tn ----
            f32x4 tn0[2], tn1[2];
            {
                const unsigned char* bb = smem + (size_t)16 * 6144 + lane * 16;
#pragma unroll
                for (int cf = 0; cf < 4; cf++) {
                    bf16x8 bf = ld_frag(bb + cf * 1024);
#pragma unroll
                    for (int mt = 0; mt < 2; mt++) MFMA(afx[mt], bf, acc[mt][cf]);
                }
                bf16x8 bn0 = ld_frag(bb + 4 * 1024);
                bf16x8 bn1 = ld_frag(bb + 5 * 1024);
#pragma unroll
                for (int mt = 0; mt < 2; mt++) {
                    f32x4 z4 = {0.f, 0.f, 0.f, 0.f};
                    tn0[mt] = __builtin_amdgcn_mfma_f32_16x16x32_bf16(afx[mt], bn0, z4, 0, 0, 0);
                    tn1[mt] = __builtin_amdgcn_mfma_f32_16x16x32_bf16(afx[mt], bn1, z4, 0, 0, 0);
                }
            }

            // ---- 16 h-stages ----
            if (hasA) {
#pragma unroll
                for (int s = 0; s < 8; s++) {
                    const unsigned char* bb = smem + (size_t)s * 6144 + lane * 16;
#pragma unroll
                    for (int cf = 0; cf < 6; cf++) {
                        bf16x8 bf = ld_frag(bb + cf * 1024);
#pragma unroll
                        for (int mt = 0; mt < 2; mt++) MFMA(rA[s][mt].v, bf, acc[mt][cf]);
                    }
                }
            }
            if (hasL) {
#pragma unroll
                for (int s = 0; s < 8; s++) {
                    const unsigned char* bb = smem + (size_t)(8 + s) * 6144 + lane * 16;
#pragma unroll
                    for (int cf = 0; cf < 6; cf++) {
                        bf16x8 bf = ld_frag(bb + cf * 1024);
#pragma unroll
                        for (int mt = 0; mt < 2; mt++) MFMA(rL[s][mt].v, bf, acc[mt][cf]);
                    }
                }
            }

            // ---- back-pressure before overwriting slot (j, i%3) ----
            if (j < Nx - 1 && i >= 3) wait_ge(cons + j, 8u * (unsigned)(i - 2));

            // ---- epilogue: gates, state update, coalesced sc0sc1 stores ----
            char* sO = hbg + (size_t)(j * 3 + (i % 3)) * 16384;
#pragma unroll
            for (int mt = 0; mt < 2; mt++) {
#pragma unroll
                for (int e = 0; e < 4; e++) {
                    int m = mt * 16 + q * 4 + e;
                    float rv0 = sigf(acc[mt][0][e] + bR0);
                    float zv0 = sigf(acc[mt][2][e] + bZ0);
                    float nv0 = tanhf_fast(tn0[mt][e] + bN0 + rv0 * acc[mt][4][e]);
                    float rv1 = sigf(acc[mt][1][e] + bR1);
                    float zv1 = sigf(acc[mt][3][e] + bZ1);
                    float nv1 = tanhf_fast(tn1[mt][e] + bN1 + rv1 * acc[mt][5][e]);
                    float hs0 = 0.f, hs1 = 0.f;
                    if (hasA) {
                        unsigned v = hsA[mt * 4 + e];
                        hs0 += bf16_lo(v); hs1 += bf16_hi(v);
                    }
                    if (hasL) {
                        unsigned v = hsL[mt * 4 + e];
                        hs0 += bf16_lo(v); hs1 += bf16_hi(v);
                    }
                    float h0 = (1.f - zv0) * nv0 + 0.5f * zv0 * hs0;
                    float h1 = (1.f - zv1) * nv1 + 0.5f * zv1 * hs1;
                    st4_sc01(sO + (size_t)g * 2048 + (size_t)m * 64 + l16 * 4,
                             bf16_bits(h0) | (bf16_bits(h1) << 16));
                }
            }

            wait_vm0();   // h stores at the L3 coherence point
            if (lane == 0) {
                __hip_atomic_fetch_add(prog + j, 1u, __ATOMIC_RELAXED,
                                       __HIP_MEMORY_SCOPE_AGENT);
                if (hasL)
                    __hip_atomic_fetch_add(cons + j - 1, 1u, __ATOMIC_RELAXED,
                                           __HIP_MEMORY_SCOPE_AGENT);
            }
        }
    }
}

// ---------------------------------------------------------------------------
// Output: logits = hcat @ W_out + b_out, then log_softmax. One wave per batch.
// ---------------------------------------------------------------------------
__global__ __launch_bounds__(64) void out_kernel(const char* __restrict__ hbuf,
    const float* __restrict__ Wout, const float* __restrict__ bout,
    float* __restrict__ out)
{
    int b = blockIdx.x;
    int tt = threadIdx.x;
    float accv[10];
#pragma unroll
    for (int o = 0; o < 10; o++) accv[o] = 0.f;
    for (int it = 0; it < 16; ++it) {
        int k = it * 64 + tt;
        int a = k >> 8, c = k & 255;
        int Ny = 29 - (a & 1), Nx = 29 - ((a >> 1) & 1);
        int G  = a * 8 + (b >> 5);
        int c31 = c & 31;
        int pos = ((c31 & 15) << 1) | (c31 >> 4);
        const __bf16* hp = (const __bf16*)(hbuf + (size_t)G * 1425408
                           + (size_t)((Nx - 1) * 3 + (Ny - 1) % 3) * 16384
                           + (size_t)(c >> 5) * 2048 + (size_t)(b & 31) * 64
                           + (size_t)pos * 2);
        float h = (float)(*hp);
        const float* wr = Wout + k * 10;
#pragma unroll
        for (int o = 0; o < 10; o++) accv[o] += h * wr[o];
    }
#pragma unroll
    for (int off = 32; off > 0; off >>= 1)
#pragma unroll
        for (int o = 0; o < 10; o++) accv[o] += __shfl_down(accv[o], off, 64);
    if (tt == 0) {
        float l[10];
#pragma unroll
        for (int o = 0; o < 10; o++) l[o] = accv[o] + bout[o];
        float mx = l[0];
#pragma unroll
        for (int o = 1; o < 10; o++) mx = fmaxf(mx, l[o]);
        float se = 0.f;
#pragma unroll
        for (int o = 0; o < 10; o++) se += __expf(l[o] - mx);
        float lse = mx + __logf(se);
#pragma unroll
        for (int o = 0; o < 10; o++) out[b * 10 + o] = l[o] - lse;
    }
}

extern "C" void kernel_launch(void* const* d_in, const int* in_sizes, int n_in,
                              void* d_out, int out_size, void* d_ws, size_t ws_size,
                              hipStream_t stream) {
    const float* x    = (const float*)d_in[0];
    const float* Wx   = (const float*)d_in[1];
    const float* Uh   = (const float*)d_in[2];
    const float* Uh2  = (const float*)d_in[3];
    const float* b    = (const float*)d_in[4];
    const float* Wout = (const float*)d_in[5];
    const float* bout = (const float*)d_in[6];
    float* out = (float*)d_out;

    char* ws = (char*)d_ws;
    const size_t PACK_PAD   = 3407872;
    const size_t XPACK_END  = 31457280;     // pack + xpack (padded)
    const size_t HBUF_BYTES = 45613056;     // 32 * 29 * 3 * 16384
    const size_t FLAG_BYTES = 8192;
    bool use_xp = (ws_size >= XPACK_END + HBUF_BYTES + FLAG_BYTES);

    uint4*  packW = (uint4*)ws;
    uint4*  xpack = use_xp ? (uint4*)(ws + PACK_PAD) : nullptr;
    size_t  hbuf_off = use_xp ? XPACK_END : PACK_PAD;
    char*   hbuf  = ws + hbuf_off;
    unsigned* flags = (unsigned*)(ws + hbuf_off + HBUF_BYTES);

    (void)hipFuncSetAttribute((const void*)persist_kernel,
                              hipFuncAttributeMaxDynamicSharedMemorySize, 104448);

    hipMemsetAsync(flags, 0, FLAG_BYTES, stream);
    pack_kernel<<<816, 256, 0, stream>>>(Wx, Uh, Uh2, packW);
    if (use_xp)
        xpack_kernel<<<6728, 256, 0, stream>>>(x, xpack);

    void* args[] = { (void*)&x, (void*)&xpack, (void*)&packW, (void*)&b,
                     (void*)&hbuf, (void*)&flags };
    hipLaunchCooperativeKernel((void*)persist_kernel, dim3(256), dim3(512),
                               args, 104448, stream);

    out_kernel<<<256, 64, 0, stream>>>(hbuf, Wout, bout, out);
}